// Round 2
// baseline (422.799 us; speedup 1.0000x reference)
//
#include <hip/hip_runtime.h>
#include <hip/hip_bf16.h>

#define NEMB 16
#define NHID 64

__device__ __forceinline__ unsigned int pack_bf16x2(float lo, float hi) {
    unsigned int ul = __float_as_uint(lo);
    unsigned int uh = __float_as_uint(hi);
    // round-half-up to bf16
    return ((ul + 0x8000u) >> 16) | ((uh + 0x8000u) & 0xffff0000u);
}

// ---------------------------------------------------------------------------
// Kernel P: per-node precompute of layer-1 partials (bf16-packed).
//   Htop[n][j] = sum_k emb[n][k] * W1[k][j] + b1[j]     (b1 folded here)
//   Hbot[n][j] = sum_k emb[n][k] * W1[16+k][j]
// ---------------------------------------------------------------------------
__global__ __launch_bounds__(256) void precompute_h1_kernel(
        const float* __restrict__ emb,
        const float* __restrict__ W1, const float* __restrict__ b1,
        unsigned int* __restrict__ Htop, unsigned int* __restrict__ Hbot,
        int nNodes) {
    __shared__ float sW1[32 * 64];
    __shared__ float sB1[64];
    for (int i = threadIdx.x; i < 2048; i += 256) sW1[i] = W1[i];
    if (threadIdx.x < 64) sB1[threadIdx.x] = b1[threadIdx.x];
    __syncthreads();

    int n = blockIdx.x * 256 + threadIdx.x;
    if (n >= nNodes) return;

    float e[16];
    const float4* pe = reinterpret_cast<const float4*>(emb + (size_t)n * NEMB);
#pragma unroll
    for (int q = 0; q < 4; ++q) {
        float4 v = pe[q];
        e[4 * q + 0] = v.x; e[4 * q + 1] = v.y;
        e[4 * q + 2] = v.z; e[4 * q + 3] = v.w;
    }

    unsigned int packT[32], packB[32];
#pragma unroll
    for (int j = 0; j < 64; j += 2) {
        float t0 = sB1[j], t1 = sB1[j + 1];
        float c0 = 0.0f, c1 = 0.0f;
#pragma unroll
        for (int k = 0; k < 16; ++k) {
            t0 = fmaf(e[k], sW1[k * 64 + j + 0], t0);
            t1 = fmaf(e[k], sW1[k * 64 + j + 1], t1);
            c0 = fmaf(e[k], sW1[(16 + k) * 64 + j + 0], c0);
            c1 = fmaf(e[k], sW1[(16 + k) * 64 + j + 1], c1);
        }
        packT[j / 2] = pack_bf16x2(t0, t1);
        packB[j / 2] = pack_bf16x2(c0, c1);
    }

    uint4* ot = reinterpret_cast<uint4*>(Htop + (size_t)n * 32);
    uint4* ob = reinterpret_cast<uint4*>(Hbot + (size_t)n * 32);
#pragma unroll
    for (int q = 0; q < 8; ++q) {
        ot[q] = make_uint4(packT[4 * q + 0], packT[4 * q + 1], packT[4 * q + 2], packT[4 * q + 3]);
        ob[q] = make_uint4(packB[4 * q + 0], packB[4 * q + 1], packB[4 * q + 2], packB[4 * q + 3]);
    }
}

// ---------------------------------------------------------------------------
// Kernel E: per-edge MLP using precomputed layer-1 partials.
//   h1 = relu(Htop[s] + Hbot[d]);  h2 = relu(h1@W2 + b2);  p = sigmoid(h2@W3+b3)
// layer-3 folded into the layer-2 j-loop (no h2 array).
// ---------------------------------------------------------------------------
__global__ __launch_bounds__(256) void edge_mlp2_kernel(
        const unsigned int* __restrict__ Htop, const unsigned int* __restrict__ Hbot,
        const int* __restrict__ ei,
        const float* __restrict__ W2, const float* __restrict__ b2,
        const float* __restrict__ W3, const float* __restrict__ b3,
        float* __restrict__ out, int nE) {
    __shared__ __align__(16) float sW2[64 * 32];
    __shared__ float sB2[32];
    __shared__ float sW3[32];
    __shared__ float sB3;
    for (int i = threadIdx.x; i < 2048; i += 256) sW2[i] = W2[i];
    if (threadIdx.x < 32) {
        sB2[threadIdx.x] = b2[threadIdx.x];
        sW3[threadIdx.x] = W3[threadIdx.x];
    }
    if (threadIdx.x == 0) sB3 = b3[0];
    __syncthreads();

    int e = blockIdx.x * 256 + threadIdx.x;
    if (e >= nE) return;

    int s = ei[e];
    int d = ei[nE + e];

    const uint4* pt = reinterpret_cast<const uint4*>(Htop + (size_t)s * 32);
    const uint4* pb = reinterpret_cast<const uint4*>(Hbot + (size_t)d * 32);

    float h1[64];
#pragma unroll
    for (int q = 0; q < 8; ++q) {
        uint4 t = pt[q];
        uint4 b = pb[q];
        unsigned int tw[4] = {t.x, t.y, t.z, t.w};
        unsigned int bw[4] = {b.x, b.y, b.z, b.w};
#pragma unroll
        for (int r = 0; r < 4; ++r) {
            float lo = __uint_as_float(tw[r] << 16) + __uint_as_float(bw[r] << 16);
            float hi = __uint_as_float(tw[r] & 0xffff0000u) +
                       __uint_as_float(bw[r] & 0xffff0000u);
            h1[8 * q + 2 * r + 0] = fmaxf(lo, 0.0f);
            h1[8 * q + 2 * r + 1] = fmaxf(hi, 0.0f);
        }
    }

    float acc = sB3;
#pragma unroll
    for (int j = 0; j < 32; j += 4) {
        float a0 = sB2[j + 0], a1 = sB2[j + 1], a2 = sB2[j + 2], a3 = sB2[j + 3];
#pragma unroll
        for (int k = 0; k < 64; ++k) {
            float4 w = *reinterpret_cast<const float4*>(sW2 + k * 32 + j);
            a0 = fmaf(h1[k], w.x, a0);
            a1 = fmaf(h1[k], w.y, a1);
            a2 = fmaf(h1[k], w.z, a2);
            a3 = fmaf(h1[k], w.w, a3);
        }
        acc = fmaf(fmaxf(a0, 0.0f), sW3[j + 0], acc);
        acc = fmaf(fmaxf(a1, 0.0f), sW3[j + 1], acc);
        acc = fmaf(fmaxf(a2, 0.0f), sW3[j + 2], acc);
        acc = fmaf(fmaxf(a3, 0.0f), sW3[j + 3], acc);
    }

    out[e] = 1.0f / (1.0f + __expf(-acc));
}

// ---------------------------------------------------------------------------
// Fallback: per-edge full MLP (no workspace), f32 output.
// ---------------------------------------------------------------------------
__global__ __launch_bounds__(256) void edge_mlp_naive_kernel(
        const float* __restrict__ emb, const int* __restrict__ ei,
        const float* __restrict__ W1, const float* __restrict__ b1,
        const float* __restrict__ W2, const float* __restrict__ b2,
        const float* __restrict__ W3, const float* __restrict__ b3,
        float* __restrict__ out, int nE) {
    __shared__ __align__(16) float sW1[32 * 64];
    __shared__ __align__(16) float sW2[64 * 32];
    __shared__ float sW3[32];
    __shared__ float sB1[64];
    __shared__ float sB2[32];
    __shared__ float sB3;
    for (int i = threadIdx.x; i < 2048; i += 256) {
        sW1[i] = W1[i];
        sW2[i] = W2[i];
    }
    if (threadIdx.x < 64) sB1[threadIdx.x] = b1[threadIdx.x];
    if (threadIdx.x < 32) {
        sW3[threadIdx.x] = W3[threadIdx.x];
        sB2[threadIdx.x] = b2[threadIdx.x];
    }
    if (threadIdx.x == 0) sB3 = b3[0];
    __syncthreads();

    int e = blockIdx.x * 256 + threadIdx.x;
    if (e >= nE) return;

    int s = ei[e];
    int d = ei[nE + e];

    float f[32];
    const float4* ps = reinterpret_cast<const float4*>(emb + (size_t)s * NEMB);
    const float4* pd = reinterpret_cast<const float4*>(emb + (size_t)d * NEMB);
#pragma unroll
    for (int q = 0; q < 4; ++q) {
        float4 v = ps[q];
        f[4 * q + 0] = v.x; f[4 * q + 1] = v.y; f[4 * q + 2] = v.z; f[4 * q + 3] = v.w;
    }
#pragma unroll
    for (int q = 0; q < 4; ++q) {
        float4 v = pd[q];
        f[16 + 4 * q + 0] = v.x; f[16 + 4 * q + 1] = v.y;
        f[16 + 4 * q + 2] = v.z; f[16 + 4 * q + 3] = v.w;
    }

    float h1[64];
#pragma unroll
    for (int j = 0; j < 64; j += 4) {
        float a0 = sB1[j + 0], a1 = sB1[j + 1], a2 = sB1[j + 2], a3 = sB1[j + 3];
#pragma unroll
        for (int k = 0; k < 32; ++k) {
            float4 w = *reinterpret_cast<const float4*>(sW1 + k * 64 + j);
            a0 = fmaf(f[k], w.x, a0);
            a1 = fmaf(f[k], w.y, a1);
            a2 = fmaf(f[k], w.z, a2);
            a3 = fmaf(f[k], w.w, a3);
        }
        h1[j + 0] = fmaxf(a0, 0.0f);
        h1[j + 1] = fmaxf(a1, 0.0f);
        h1[j + 2] = fmaxf(a2, 0.0f);
        h1[j + 3] = fmaxf(a3, 0.0f);
    }

    float acc = sB3;
#pragma unroll
    for (int j = 0; j < 32; j += 4) {
        float a0 = sB2[j + 0], a1 = sB2[j + 1], a2 = sB2[j + 2], a3 = sB2[j + 3];
#pragma unroll
        for (int k = 0; k < 64; ++k) {
            float4 w = *reinterpret_cast<const float4*>(sW2 + k * 32 + j);
            a0 = fmaf(h1[k], w.x, a0);
            a1 = fmaf(h1[k], w.y, a1);
            a2 = fmaf(h1[k], w.z, a2);
            a3 = fmaf(h1[k], w.w, a3);
        }
        acc = fmaf(fmaxf(a0, 0.0f), sW3[j + 0], acc);
        acc = fmaf(fmaxf(a1, 0.0f), sW3[j + 1], acc);
        acc = fmaf(fmaxf(a2, 0.0f), sW3[j + 2], acc);
        acc = fmaf(fmaxf(a3, 0.0f), sW3[j + 3], acc);
    }

    out[e] = 1.0f / (1.0f + __expf(-acc));
}

// ---------------------------------------------------------------------------
// Kernel A: edge_index (int32) -> float32 copy into out[E .. 3E)
// ---------------------------------------------------------------------------
__global__ __launch_bounds__(256) void edge_idx_copy_kernel(
        const int* __restrict__ ei, float* __restrict__ out, int n) {
    int i = (blockIdx.x * 256 + threadIdx.x) * 4;
    if (i + 4 <= n) {
        int4 a = *reinterpret_cast<const int4*>(ei + i);
        float4 r = make_float4((float)a.x, (float)a.y, (float)a.z, (float)a.w);
        *reinterpret_cast<float4*>(out + i) = r;
    } else {
        for (; i < n; ++i) out[i] = (float)ei[i];
    }
}

extern "C" void kernel_launch(void* const* d_in, const int* in_sizes, int n_in,
                              void* d_out, int out_size, void* d_ws, size_t ws_size,
                              hipStream_t stream) {
    const float* emb = (const float*)d_in[0];
    const int*   ei  = (const int*)d_in[1];
    const float* W1  = (const float*)d_in[2];
    const float* b1  = (const float*)d_in[3];
    const float* W2  = (const float*)d_in[4];
    const float* b2  = (const float*)d_in[5];
    const float* W3  = (const float*)d_in[6];
    const float* b3  = (const float*)d_in[7];

    const int nNodes = in_sizes[0] / NEMB;   // 100000
    const int n2E    = in_sizes[1];          // 2 * E
    const int nE     = n2E / 2;              // E

    float* out = (float*)d_out;  // f32: [E probs][2E edge indices]

    const size_t tbl_bytes = (size_t)nNodes * 32 * sizeof(unsigned int);  // 12.8 MB
    const bool use_ws = (ws_size >= 2 * tbl_bytes);

    if (use_ws) {
        unsigned int* Htop = (unsigned int*)d_ws;
        unsigned int* Hbot = Htop + (size_t)nNodes * 32;

        precompute_h1_kernel<<<(nNodes + 255) / 256, 256, 0, stream>>>(
            emb, W1, b1, Htop, Hbot, nNodes);
        edge_mlp2_kernel<<<(nE + 255) / 256, 256, 0, stream>>>(
            Htop, Hbot, ei, W2, b2, W3, b3, out, nE);
    } else {
        edge_mlp_naive_kernel<<<(nE + 255) / 256, 256, 0, stream>>>(
            emb, ei, W1, b1, W2, b2, W3, b3, out, nE);
    }

    edge_idx_copy_kernel<<<((n2E + 3) / 4 + 255) / 256, 256, 0, stream>>>(
        ei, out + nE, n2E);
}

// Round 3
// 179.883 us; speedup vs baseline: 2.3504x; 2.3504x over previous
//
#include <hip/hip_runtime.h>
#include <hip/hip_bf16.h>

#define NEMB 16
#define NHID 64

typedef short s16x8 __attribute__((ext_vector_type(8)));
typedef float f32x4 __attribute__((ext_vector_type(4)));

__device__ __forceinline__ unsigned int pack_bf16x2(float lo, float hi) {
    unsigned int ul = __float_as_uint(lo);
    unsigned int uh = __float_as_uint(hi);
    return ((ul + 0x8000u) >> 16) | ((uh + 0x8000u) & 0xffff0000u);
}

// ---------------------------------------------------------------------------
// Kernel P: per-node precompute of layer-1 partials (bf16-packed, 64 per node).
//   Htop[n][j] = emb[n] @ W1[0:16, j] + b1[j]
//   Hbot[n][j] = emb[n] @ W1[16:32, j]
// ---------------------------------------------------------------------------
__global__ __launch_bounds__(256) void precompute_h1_kernel(
        const float* __restrict__ emb,
        const float* __restrict__ W1, const float* __restrict__ b1,
        unsigned int* __restrict__ Htop, unsigned int* __restrict__ Hbot,
        int nNodes) {
    __shared__ float sW1[32 * 64];
    __shared__ float sB1[64];
    for (int i = threadIdx.x; i < 2048; i += 256) sW1[i] = W1[i];
    if (threadIdx.x < 64) sB1[threadIdx.x] = b1[threadIdx.x];
    __syncthreads();

    int n = blockIdx.x * 256 + threadIdx.x;
    if (n >= nNodes) return;

    float e[16];
    const float4* pe = reinterpret_cast<const float4*>(emb + (size_t)n * NEMB);
#pragma unroll
    for (int q = 0; q < 4; ++q) {
        float4 v = pe[q];
        e[4 * q + 0] = v.x; e[4 * q + 1] = v.y;
        e[4 * q + 2] = v.z; e[4 * q + 3] = v.w;
    }

    unsigned int packT[32], packB[32];
#pragma unroll
    for (int j = 0; j < 64; j += 2) {
        float t0 = sB1[j], t1 = sB1[j + 1];
        float c0 = 0.0f, c1 = 0.0f;
#pragma unroll
        for (int k = 0; k < 16; ++k) {
            t0 = fmaf(e[k], sW1[k * 64 + j + 0], t0);
            t1 = fmaf(e[k], sW1[k * 64 + j + 1], t1);
            c0 = fmaf(e[k], sW1[(16 + k) * 64 + j + 0], c0);
            c1 = fmaf(e[k], sW1[(16 + k) * 64 + j + 1], c1);
        }
        packT[j / 2] = pack_bf16x2(t0, t1);
        packB[j / 2] = pack_bf16x2(c0, c1);
    }

    uint4* ot = reinterpret_cast<uint4*>(Htop + (size_t)n * 32);
    uint4* ob = reinterpret_cast<uint4*>(Hbot + (size_t)n * 32);
#pragma unroll
    for (int q = 0; q < 8; ++q) {
        ot[q] = make_uint4(packT[4 * q + 0], packT[4 * q + 1], packT[4 * q + 2], packT[4 * q + 3]);
        ob[q] = make_uint4(packB[4 * q + 0], packB[4 * q + 1], packB[4 * q + 2], packB[4 * q + 3]);
    }
}

// ---------------------------------------------------------------------------
// Kernel E (MFMA): 16 edges per wave per iteration.
//  A-frag (16x16x32 bf16): lane l holds h1[edge = l&15][k = (l>>4)*8 + i]
//  B-frag: lane l holds W2[k = (l>>4)*8 + i][col = l&15 (+16 for tile 1)]
//  D: lane l holds h2[row = (l>>4)*4 + r][col = l&15 (+16)]
//  Layer 3: per-lane dot with W3, then shfl_xor reduce over the 16-lane group.
// ---------------------------------------------------------------------------
#define EDGES_PER_ITER 64   // per block (4 waves x 16 edges)
#define ITERS 8             // 512 edges per block

__device__ __forceinline__ s16x8 build_a_frag(const unsigned short* rt,
                                              const unsigned short* rb) {
    uint4 t = *reinterpret_cast<const uint4*>(rt);
    uint4 b = *reinterpret_cast<const uint4*>(rb);
    unsigned int tu[4] = {t.x, t.y, t.z, t.w};
    unsigned int bu[4] = {b.x, b.y, b.z, b.w};
    union { unsigned int u[4]; s16x8 v; } cv;
#pragma unroll
    for (int r = 0; r < 4; ++r) {
        float lo = __uint_as_float(tu[r] << 16) + __uint_as_float(bu[r] << 16);
        float hi = __uint_as_float(tu[r] & 0xffff0000u) +
                   __uint_as_float(bu[r] & 0xffff0000u);
        lo = fmaxf(lo, 0.0f);
        hi = fmaxf(hi, 0.0f);
        cv.u[r] = pack_bf16x2(lo, hi);
    }
    return cv.v;
}

__global__ __launch_bounds__(256) void edge_mfma_kernel(
        const unsigned short* __restrict__ Htop,
        const unsigned short* __restrict__ Hbot,
        const int* __restrict__ ei,
        const float* __restrict__ W2, const float* __restrict__ b2,
        const float* __restrict__ W3, const float* __restrict__ b3,
        float* __restrict__ out, int nE) {
    const int tid = threadIdx.x;
    const int w = tid >> 6;        // wave id 0..3
    const int l = tid & 63;        // lane
    const int lr = l & 15;         // edge slot / output col
    const int lc = l >> 4;         // k-chunk / row group

    // --- Build W2 B-fragments in registers (one-time per block) ---
    s16x8 Bf[2][2];  // [ntile][khalf]
#pragma unroll
    for (int t = 0; t < 2; ++t) {
#pragma unroll
        for (int h = 0; h < 2; ++h) {
            s16x8 f;
#pragma unroll
            for (int i = 0; i < 8; ++i) {
                int k = h * 32 + lc * 8 + i;
                int n = t * 16 + lr;
                float v = W2[k * 32 + n];
                f[i] = (short)((__float_as_uint(v) + 0x8000u) >> 16);
            }
            Bf[t][h] = f;
        }
    }
    const float b2v0 = b2[lr], b2v1 = b2[16 + lr];
    const float w3v0 = W3[lr], w3v1 = W3[16 + lr];
    const float b3v = b3[0];

#pragma unroll 1
    for (int it = 0; it < ITERS; ++it) {
        int eb = blockIdx.x * (EDGES_PER_ITER * ITERS) + it * EDGES_PER_ITER + w * 16;
        if (eb >= nE) break;
        int e = eb + lr;
        int ec = e < nE ? e : (nE - 1);
        int s = ei[ec];
        int d = ei[nE + ec];

        const unsigned short* rt = Htop + (size_t)s * 64;
        const unsigned short* rb = Hbot + (size_t)d * 64;

        // k-half 0: elements lc*8 .. lc*8+7 ; k-half 1: 32 + lc*8 ..
        s16x8 A0 = build_a_frag(rt + lc * 8, rb + lc * 8);
        s16x8 A1 = build_a_frag(rt + 32 + lc * 8, rb + 32 + lc * 8);

        f32x4 acc0 = {0.f, 0.f, 0.f, 0.f};
        f32x4 acc1 = {0.f, 0.f, 0.f, 0.f};
        acc0 = __builtin_amdgcn_mfma_f32_16x16x32_bf16(A0, Bf[0][0], acc0, 0, 0, 0);
        acc0 = __builtin_amdgcn_mfma_f32_16x16x32_bf16(A1, Bf[0][1], acc0, 0, 0, 0);
        acc1 = __builtin_amdgcn_mfma_f32_16x16x32_bf16(A0, Bf[1][0], acc1, 0, 0, 0);
        acc1 = __builtin_amdgcn_mfma_f32_16x16x32_bf16(A1, Bf[1][1], acc1, 0, 0, 0);

        // Layer 3: v[r] = sum_col relu(h2)*W3, reduce over 16-lane col group
        float v0, v1, v2, v3;
        {
            float h2a, h2b;
            h2a = fmaxf(acc0[0] + b2v0, 0.f); h2b = fmaxf(acc1[0] + b2v1, 0.f);
            v0 = h2a * w3v0 + h2b * w3v1;
            h2a = fmaxf(acc0[1] + b2v0, 0.f); h2b = fmaxf(acc1[1] + b2v1, 0.f);
            v1 = h2a * w3v0 + h2b * w3v1;
            h2a = fmaxf(acc0[2] + b2v0, 0.f); h2b = fmaxf(acc1[2] + b2v1, 0.f);
            v2 = h2a * w3v0 + h2b * w3v1;
            h2a = fmaxf(acc0[3] + b2v0, 0.f); h2b = fmaxf(acc1[3] + b2v1, 0.f);
            v3 = h2a * w3v0 + h2b * w3v1;
        }
#pragma unroll
        for (int m = 1; m < 16; m <<= 1) {
            v0 += __shfl_xor(v0, m);
            v1 += __shfl_xor(v1, m);
            v2 += __shfl_xor(v2, m);
            v3 += __shfl_xor(v3, m);
        }

        if (lr == 0) {
            float4 o;
            o.x = 1.0f / (1.0f + __expf(-(v0 + b3v)));
            o.y = 1.0f / (1.0f + __expf(-(v1 + b3v)));
            o.z = 1.0f / (1.0f + __expf(-(v2 + b3v)));
            o.w = 1.0f / (1.0f + __expf(-(v3 + b3v)));
            int base = eb + lc * 4;   // rows lc*4 .. lc*4+3
            if (base + 4 <= nE) {
                *reinterpret_cast<float4*>(out + base) = o;
            } else {
                float ov[4] = {o.x, o.y, o.z, o.w};
                for (int r = 0; r < 4; ++r)
                    if (base + r < nE) out[base + r] = ov[r];
            }
        }
    }
}

// ---------------------------------------------------------------------------
// Fallback: per-edge full MLP (no workspace), f32 output.
// ---------------------------------------------------------------------------
__global__ __launch_bounds__(256) void edge_mlp_naive_kernel(
        const float* __restrict__ emb, const int* __restrict__ ei,
        const float* __restrict__ W1, const float* __restrict__ b1,
        const float* __restrict__ W2, const float* __restrict__ b2,
        const float* __restrict__ W3, const float* __restrict__ b3,
        float* __restrict__ out, int nE) {
    __shared__ __align__(16) float sW1[32 * 64];
    __shared__ __align__(16) float sW2[64 * 32];
    __shared__ float sW3[32];
    __shared__ float sB1[64];
    __shared__ float sB2[32];
    __shared__ float sB3;
    for (int i = threadIdx.x; i < 2048; i += 256) {
        sW1[i] = W1[i];
        sW2[i] = W2[i];
    }
    if (threadIdx.x < 64) sB1[threadIdx.x] = b1[threadIdx.x];
    if (threadIdx.x < 32) {
        sW3[threadIdx.x] = W3[threadIdx.x];
        sB2[threadIdx.x] = b2[threadIdx.x];
    }
    if (threadIdx.x == 0) sB3 = b3[0];
    __syncthreads();

    int e = blockIdx.x * 256 + threadIdx.x;
    if (e >= nE) return;

    int s = ei[e];
    int d = ei[nE + e];

    float f[32];
    const float4* ps = reinterpret_cast<const float4*>(emb + (size_t)s * NEMB);
    const float4* pd = reinterpret_cast<const float4*>(emb + (size_t)d * NEMB);
#pragma unroll
    for (int q = 0; q < 4; ++q) {
        float4 v = ps[q];
        f[4 * q + 0] = v.x; f[4 * q + 1] = v.y; f[4 * q + 2] = v.z; f[4 * q + 3] = v.w;
    }
#pragma unroll
    for (int q = 0; q < 4; ++q) {
        float4 v = pd[q];
        f[16 + 4 * q + 0] = v.x; f[16 + 4 * q + 1] = v.y;
        f[16 + 4 * q + 2] = v.z; f[16 + 4 * q + 3] = v.w;
    }

    float h1[64];
#pragma unroll
    for (int j = 0; j < 64; j += 4) {
        float a0 = sB1[j + 0], a1 = sB1[j + 1], a2 = sB1[j + 2], a3 = sB1[j + 3];
#pragma unroll
        for (int k = 0; k < 32; ++k) {
            float4 wv = *reinterpret_cast<const float4*>(sW1 + k * 64 + j);
            a0 = fmaf(f[k], wv.x, a0);
            a1 = fmaf(f[k], wv.y, a1);
            a2 = fmaf(f[k], wv.z, a2);
            a3 = fmaf(f[k], wv.w, a3);
        }
        h1[j + 0] = fmaxf(a0, 0.0f);
        h1[j + 1] = fmaxf(a1, 0.0f);
        h1[j + 2] = fmaxf(a2, 0.0f);
        h1[j + 3] = fmaxf(a3, 0.0f);
    }

    float acc = sB3;
#pragma unroll
    for (int j = 0; j < 32; j += 4) {
        float a0 = sB2[j + 0], a1 = sB2[j + 1], a2 = sB2[j + 2], a3 = sB2[j + 3];
#pragma unroll
        for (int k = 0; k < 64; ++k) {
            float4 wv = *reinterpret_cast<const float4*>(sW2 + k * 32 + j);
            a0 = fmaf(h1[k], wv.x, a0);
            a1 = fmaf(h1[k], wv.y, a1);
            a2 = fmaf(h1[k], wv.z, a2);
            a3 = fmaf(h1[k], wv.w, a3);
        }
        acc = fmaf(fmaxf(a0, 0.0f), sW3[j + 0], acc);
        acc = fmaf(fmaxf(a1, 0.0f), sW3[j + 1], acc);
        acc = fmaf(fmaxf(a2, 0.0f), sW3[j + 2], acc);
        acc = fmaf(fmaxf(a3, 0.0f), sW3[j + 3], acc);
    }

    out[e] = 1.0f / (1.0f + __expf(-acc));
}

// ---------------------------------------------------------------------------
// Kernel A: edge_index (int32) -> float32 copy into out[E .. 3E)
// ---------------------------------------------------------------------------
__global__ __launch_bounds__(256) void edge_idx_copy_kernel(
        const int* __restrict__ ei, float* __restrict__ out, int n) {
    int i = (blockIdx.x * 256 + threadIdx.x) * 4;
    if (i + 4 <= n) {
        int4 a = *reinterpret_cast<const int4*>(ei + i);
        float4 r = make_float4((float)a.x, (float)a.y, (float)a.z, (float)a.w);
        *reinterpret_cast<float4*>(out + i) = r;
    } else {
        for (; i < n; ++i) out[i] = (float)ei[i];
    }
}

extern "C" void kernel_launch(void* const* d_in, const int* in_sizes, int n_in,
                              void* d_out, int out_size, void* d_ws, size_t ws_size,
                              hipStream_t stream) {
    const float* emb = (const float*)d_in[0];
    const int*   ei  = (const int*)d_in[1];
    const float* W1  = (const float*)d_in[2];
    const float* b1  = (const float*)d_in[3];
    const float* W2  = (const float*)d_in[4];
    const float* b2  = (const float*)d_in[5];
    const float* W3  = (const float*)d_in[6];
    const float* b3  = (const float*)d_in[7];

    const int nNodes = in_sizes[0] / NEMB;   // 100000
    const int n2E    = in_sizes[1];          // 2 * E
    const int nE     = n2E / 2;              // E

    float* out = (float*)d_out;  // f32: [E probs][2E edge indices]

    const size_t tbl_bytes = (size_t)nNodes * 64 * sizeof(unsigned short);  // 12.8 MB
    const bool use_ws = (ws_size >= 2 * tbl_bytes);

    if (use_ws) {
        unsigned int* Htop = (unsigned int*)d_ws;
        unsigned int* Hbot = Htop + (size_t)nNodes * 32;

        precompute_h1_kernel<<<(nNodes + 255) / 256, 256, 0, stream>>>(
            emb, W1, b1, Htop, Hbot, nNodes);

        const int epb = EDGES_PER_ITER * ITERS;  // 512
        edge_mfma_kernel<<<(nE + epb - 1) / epb, 256, 0, stream>>>(
            (const unsigned short*)Htop, (const unsigned short*)Hbot, ei,
            W2, b2, W3, b3, out, nE);
    } else {
        edge_mlp_naive_kernel<<<(nE + 255) / 256, 256, 0, stream>>>(
            emb, ei, W1, b1, W2, b2, W3, b3, out, nE);
    }

    edge_idx_copy_kernel<<<((n2E + 3) / 4 + 255) / 256, 256, 0, stream>>>(
        ei, out + nE, n2E);
}